// Round 1
// baseline (134.540 us; speedup 1.0000x reference)
//
#include <hip/hip_runtime.h>
#include <hip/hip_bf16.h>

// Problem constants
#define BB 32
#define SS 512
#define LL 8
#define HH 1024
#define DD 64

#define BM 32   // rows per block in main GEMM
#define BK 32   // K chunk
#define APAD 40 // padded LDS row stride in bf16 elems (80 B: 16B-aligned, 2-way bank alias only)

typedef __attribute__((ext_vector_type(8))) short bf16x8;
typedef __attribute__((ext_vector_type(4))) float f32x4;

__device__ __forceinline__ unsigned short f2bf(float x) {
    unsigned int u = __float_as_uint(x);
    u += 0x7FFFu + ((u >> 16) & 1u);   // round-to-nearest-even
    return (unsigned short)(u >> 16);
}

// ---------------------------------------------------------------------------
// Kernel 0: W1pT[d][h] = bf16(term_weight[h] * W1[h][d]), transposed layout
// ---------------------------------------------------------------------------
__global__ void k_prep(const float* __restrict__ W1,
                       const float* __restrict__ tw,
                       unsigned short* __restrict__ W1pT) {
    int i = blockIdx.x * 256 + threadIdx.x;   // i = h*64 + d, i < 65536
    int h = i >> 6;
    int d = i & 63;
    float val = tw[h] * W1[i];
    W1pT[d * HH + h] = f2bf(val);
}

// ---------------------------------------------------------------------------
// Kernel 1: per-position e1 and v.
//   e1[row] = relu(hidden[row]*tw @ W1 + b1) @ W2 + b2   (bf16 MFMA, tw folded)
//   v[row]  = hidden[row] @ Ws                            (fp32, fused in staging)
// Block: 256 thr (4 waves), BM=32 rows, N=64 (wave w owns cols 16w..16w+15).
// ---------------------------------------------------------------------------
__global__ __launch_bounds__(256) void k_main(
        const float* __restrict__ hidden,
        const unsigned short* __restrict__ W1pT,
        const float* __restrict__ b1,
        const float* __restrict__ W2,
        const float* __restrict__ b2,
        const float* __restrict__ Ws,
        float* __restrict__ e1,
        float* __restrict__ vout) {
    __shared__ unsigned short Alds[BM * APAD];   // 2560 B
    __shared__ unsigned short Blds[DD * APAD];   // 5120 B
    __shared__ float eplds[4][BM];               // 512 B

    const int tid = threadIdx.x;
    const int row0 = blockIdx.x * BM;

    const int ln   = tid & 63;
    const int wv   = tid >> 6;     // wave 0..3
    const int ln15 = ln & 15;
    const int quad = ln >> 4;

    // staging roles
    const int ar  = tid >> 3;         // A row 0..31
    const int ako = (tid & 7) * 4;    // A k-offset (4 floats)
    const int bd  = tid >> 2;         // B d-row 0..63
    const int bko = (tid & 3) * 8;    // B k-offset (8 bf16)

    f32x4 acc0 = {0.f, 0.f, 0.f, 0.f};
    f32x4 acc1 = {0.f, 0.f, 0.f, 0.f};
    float vp = 0.f;

    const float* arow = hidden + (size_t)(row0 + ar) * HH + ako;
    const unsigned short* brow = W1pT + (size_t)bd * HH + bko;

    for (int k0 = 0; k0 < HH; k0 += BK) {
        // ---- stage A (convert to bf16) + accumulate v partial ----
        float4 h4 = *(const float4*)(arow + k0);
        float4 w4 = *(const float4*)(Ws + k0 + ako);
        vp += h4.x * w4.x + h4.y * w4.y + h4.z * w4.z + h4.w * w4.w;
        ushort4 a4;
        a4.x = f2bf(h4.x); a4.y = f2bf(h4.y); a4.z = f2bf(h4.z); a4.w = f2bf(h4.w);
        *(ushort4*)&Alds[ar * APAD + ako] = a4;
        // ---- stage B (already bf16) ----
        *(uint4*)&Blds[bd * APAD + bko] = *(const uint4*)(brow + k0);
        __syncthreads();

        // ---- MFMA ----
        bf16x8 bfrag = *(const bf16x8*)&Blds[(wv * 16 + ln15) * APAD + quad * 8];
        bf16x8 af0   = *(const bf16x8*)&Alds[(ln15) * APAD + quad * 8];
        bf16x8 af1   = *(const bf16x8*)&Alds[(16 + ln15) * APAD + quad * 8];
        acc0 = __builtin_amdgcn_mfma_f32_16x16x32_bf16(af0, bfrag, acc0, 0, 0, 0);
        acc1 = __builtin_amdgcn_mfma_f32_16x16x32_bf16(af1, bfrag, acc1, 0, 0, 0);
        __syncthreads();
    }

    // ---- v reduction: 8 threads per row (consecutive lanes) ----
    vp += __shfl_xor(vp, 1);
    vp += __shfl_xor(vp, 2);
    vp += __shfl_xor(vp, 4);
    if ((tid & 7) == 0) vout[row0 + (tid >> 3)] = vp;

    // ---- epilogue: relu(x + b1) * W2, reduce over this wave's 16 cols ----
    const int col = wv * 16 + ln15;
    const float b1c = b1[col];
    const float w2c = W2[col];
    float ep[8];
#pragma unroll
    for (int reg = 0; reg < 4; reg++) {
        float x0 = acc0[reg] + b1c;
        float x1 = acc1[reg] + b1c;
        ep[reg]     = fmaxf(x0, 0.f) * w2c;
        ep[4 + reg] = fmaxf(x1, 0.f) * w2c;
    }
#pragma unroll
    for (int off = 1; off < 16; off <<= 1) {
#pragma unroll
        for (int i = 0; i < 8; i++) ep[i] += __shfl_xor(ep[i], off);
    }
    if (ln15 == 0) {
#pragma unroll
        for (int reg = 0; reg < 4; reg++) {
            eplds[wv][quad * 4 + reg]      = ep[reg];
            eplds[wv][16 + quad * 4 + reg] = ep[4 + reg];
        }
    }
    __syncthreads();
    if (tid < BM) {
        float e = b2[0] + eplds[0][tid] + eplds[1][tid] + eplds[2][tid] + eplds[3][tid];
        e1[row0 + tid] = e;
    }
}

// ---------------------------------------------------------------------------
// Kernel 2: span scoring. One thread per (b, s). Online softmax over j<=l.
// ---------------------------------------------------------------------------
__global__ __launch_bounds__(256) void k_span(
        const float* __restrict__ e1,
        const float* __restrict__ v,
        const int* __restrict__ seq_lengths,
        const float* __restrict__ bs,
        float* __restrict__ out) {
    int i = blockIdx.x * 256 + threadIdx.x;   // i < B*S
    int b = i >> 9;
    int s = i & (SS - 1);
    int sl = seq_lengths[b];
    float res[LL];

    if (s >= sl) {
#pragma unroll
        for (int l = 0; l < LL; l++) res[l] = 0.f;
    } else {
        const float bsv = bs[0];
        float e[LL], vv[LL];
        int base = b << 9;
#pragma unroll
        for (int j = 0; j < LL; j++) {
            int pos = s + j; if (pos > SS - 1) pos = SS - 1;
            e[j]  = e1[base + pos];
            vv[j] = v[base + pos];
        }
        // j = 0 is always valid when s < sl
        float M = e[0], Z = 1.f, W = vv[0];
        res[0] = W / Z + bsv;
#pragma unroll
        for (int l = 1; l < LL; l++) {
            if (s + l < sl) {
                float el = e[l];
                if (el > M) {
                    float c = __expf(M - el);
                    Z = Z * c + 1.f;
                    W = W * c + vv[l];
                    M = el;
                } else {
                    float p = __expf(el - M);
                    Z += p;
                    W += p * vv[l];
                }
            }
            res[l] = W / Z + bsv;
        }
    }
    float4* o = (float4*)(out + (size_t)i * LL);
    o[0] = make_float4(res[0], res[1], res[2], res[3]);
    o[1] = make_float4(res[4], res[5], res[6], res[7]);
}

extern "C" void kernel_launch(void* const* d_in, const int* in_sizes, int n_in,
                              void* d_out, int out_size, void* d_ws, size_t ws_size,
                              hipStream_t stream) {
    const float* hidden = (const float*)d_in[0];
    const int*   seqlen = (const int*)d_in[1];
    const float* tw     = (const float*)d_in[2];
    const float* W1     = (const float*)d_in[3];
    const float* b1     = (const float*)d_in[4];
    const float* W2     = (const float*)d_in[5];
    const float* b2     = (const float*)d_in[6];
    const float* Ws     = (const float*)d_in[7];
    const float* bs     = (const float*)d_in[8];
    float* out = (float*)d_out;

    // workspace layout
    unsigned short* W1pT = (unsigned short*)d_ws;                       // 131072 B
    float* e1 = (float*)((char*)d_ws + 131072);                         // 65536 B
    float* vv = (float*)((char*)d_ws + 131072 + 65536);                 // 65536 B

    // kernel 0: fold term_weight into W1, transpose, bf16
    k_prep<<<(HH * DD) / 256, 256, 0, stream>>>(W1, tw, W1pT);

    // kernel 1: per-position e1 / v
    k_main<<<(BB * SS) / BM, 256, 0, stream>>>(hidden, W1pT, b1, W2, b2, Ws, e1, vv);

    // kernel 2: span scores
    k_span<<<(BB * SS) / 256, 256, 0, stream>>>(e1, vv, seqlen, bs, out);
}

// Round 2
// 124.769 us; speedup vs baseline: 1.0783x; 1.0783x over previous
//
#include <hip/hip_runtime.h>
#include <hip/hip_bf16.h>

// Problem constants
#define BB 32
#define SS 512
#define LL 8
#define HH 1024
#define DD 64

#define BM 16        // rows per block in main GEMM
#define ROWSTR 1032  // LDS row stride in bf16 elems (2064 B: 16B-aligned, bank stride 4 -> 2-way alias = free)

typedef __attribute__((ext_vector_type(8))) short bf16x8;
typedef __attribute__((ext_vector_type(4))) float f32x4;

__device__ __forceinline__ unsigned short f2bf(float x) {
    unsigned int u = __float_as_uint(x);
    u += 0x7FFFu + ((u >> 16) & 1u);   // round-to-nearest-even
    return (unsigned short)(u >> 16);
}

// ---------------------------------------------------------------------------
// Kernel 0: W1pT[d][h] = bf16(term_weight[h] * W1[h][d]), transposed layout
// ---------------------------------------------------------------------------
__global__ void k_prep(const float* __restrict__ W1,
                       const float* __restrict__ tw,
                       unsigned short* __restrict__ W1pT) {
    int i = blockIdx.x * 256 + threadIdx.x;   // i = h*64 + d, i < 65536
    int h = i >> 6;
    int d = i & 63;
    float val = tw[h] * W1[i];
    W1pT[d * HH + h] = f2bf(val);
}

// ---------------------------------------------------------------------------
// Kernel 1: per-position e1 and v. Load-all-then-compute structure:
//   phase 1: stage full A-tile (16 rows x 1024 k, fp32->bf16) into LDS with
//            16 back-to-back float4 loads/thread (deep HBM pipeline); fuse
//            v = hidden @ Ws partial sums.
//   barrier (the only one before epilogue)
//   phase 2: 32 barrier-free MFMA iterations; B fragments read straight from
//            global W1pT (L2-resident, 128 KB shared by all 1024 blocks).
// ---------------------------------------------------------------------------
__global__ __launch_bounds__(256) void k_main(
        const float* __restrict__ hidden,
        const unsigned short* __restrict__ W1pT,
        const float* __restrict__ b1,
        const float* __restrict__ W2,
        const float* __restrict__ b2,
        const float* __restrict__ Ws,
        float* __restrict__ e1,
        float* __restrict__ vout) {
    __shared__ unsigned short Alds[BM * ROWSTR];   // 33024 B
    __shared__ float eplds[4][BM];                 // 256 B

    const int tid = threadIdx.x;
    const int row0 = blockIdx.x * BM;

    // ---- phase 1: stage A + fused v partial ----
    {
        const int r  = tid >> 4;          // 0..15: which row this thread stages
        const int co = (tid & 15) * 4;    // float offset within 64-float segment
        const float* arow = hidden + (size_t)(row0 + r) * HH + co;
        float vp = 0.f;
#pragma unroll
        for (int i = 0; i < 16; i++) {
            float4 h4 = *(const float4*)(arow + i * 64);
            float4 w4 = *(const float4*)(Ws + co + i * 64);
            vp += h4.x * w4.x + h4.y * w4.y + h4.z * w4.z + h4.w * w4.w;
            ushort4 a4;
            a4.x = f2bf(h4.x); a4.y = f2bf(h4.y); a4.z = f2bf(h4.z); a4.w = f2bf(h4.w);
            *(ushort4*)&Alds[r * ROWSTR + co + i * 64] = a4;
        }
        // v reduction across the 16 threads sharing a row
        vp += __shfl_xor(vp, 1);
        vp += __shfl_xor(vp, 2);
        vp += __shfl_xor(vp, 4);
        vp += __shfl_xor(vp, 8);
        if ((tid & 15) == 0) vout[row0 + r] = vp;
    }
    __syncthreads();

    // ---- phase 2: barrier-free MFMA loop ----
    const int wv   = tid >> 6;     // wave 0..3 -> cols 16w..16w+15
    const int ln   = tid & 63;
    const int ln15 = ln & 15;
    const int quad = ln >> 4;

    const unsigned short* bptr = W1pT + (size_t)(wv * 16 + ln15) * HH + quad * 8;
    const unsigned short* aptr = &Alds[ln15 * ROWSTR + quad * 8];

    f32x4 acc = {0.f, 0.f, 0.f, 0.f};
#pragma unroll
    for (int c = 0; c < 32; c++) {
        bf16x8 bfrag = *(const bf16x8*)(bptr + c * 32);
        bf16x8 afrag = *(const bf16x8*)(aptr + c * 32);
        acc = __builtin_amdgcn_mfma_f32_16x16x32_bf16(afrag, bfrag, acc, 0, 0, 0);
    }

    // ---- epilogue: relu(x + b1) * W2, reduce over this wave's 16 cols ----
    const int col = wv * 16 + ln15;
    const float b1c = b1[col];
    const float w2c = W2[col];
    float ep[4];
#pragma unroll
    for (int reg = 0; reg < 4; reg++) {
        ep[reg] = fmaxf(acc[reg] + b1c, 0.f) * w2c;
    }
#pragma unroll
    for (int off = 1; off < 16; off <<= 1) {
#pragma unroll
        for (int i = 0; i < 4; i++) ep[i] += __shfl_xor(ep[i], off);
    }
    if (ln15 == 0) {
#pragma unroll
        for (int reg = 0; reg < 4; reg++) eplds[wv][quad * 4 + reg] = ep[reg];
    }
    __syncthreads();
    if (tid < BM) {
        e1[row0 + tid] = b2[0] + eplds[0][tid] + eplds[1][tid] + eplds[2][tid] + eplds[3][tid];
    }
}

// ---------------------------------------------------------------------------
// Kernel 2: span scoring. One thread per (b, s). Online softmax over j<=l.
// ---------------------------------------------------------------------------
__global__ __launch_bounds__(256) void k_span(
        const float* __restrict__ e1,
        const float* __restrict__ v,
        const int* __restrict__ seq_lengths,
        const float* __restrict__ bs,
        float* __restrict__ out) {
    int i = blockIdx.x * 256 + threadIdx.x;   // i < B*S
    int b = i >> 9;
    int s = i & (SS - 1);
    int sl = seq_lengths[b];
    float res[LL];

    if (s >= sl) {
#pragma unroll
        for (int l = 0; l < LL; l++) res[l] = 0.f;
    } else {
        const float bsv = bs[0];
        float e[LL], vv[LL];
        int base = b << 9;
#pragma unroll
        for (int j = 0; j < LL; j++) {
            int pos = s + j; if (pos > SS - 1) pos = SS - 1;
            e[j]  = e1[base + pos];
            vv[j] = v[base + pos];
        }
        // j = 0 is always valid when s < sl
        float M = e[0], Z = 1.f, W = vv[0];
        res[0] = W / Z + bsv;
#pragma unroll
        for (int l = 1; l < LL; l++) {
            if (s + l < sl) {
                float el = e[l];
                if (el > M) {
                    float c = __expf(M - el);
                    Z = Z * c + 1.f;
                    W = W * c + vv[l];
                    M = el;
                } else {
                    float p = __expf(el - M);
                    Z += p;
                    W += p * vv[l];
                }
            }
            res[l] = W / Z + bsv;
        }
    }
    float4* o = (float4*)(out + (size_t)i * LL);
    o[0] = make_float4(res[0], res[1], res[2], res[3]);
    o[1] = make_float4(res[4], res[5], res[6], res[7]);
}

extern "C" void kernel_launch(void* const* d_in, const int* in_sizes, int n_in,
                              void* d_out, int out_size, void* d_ws, size_t ws_size,
                              hipStream_t stream) {
    const float* hidden = (const float*)d_in[0];
    const int*   seqlen = (const int*)d_in[1];
    const float* tw     = (const float*)d_in[2];
    const float* W1     = (const float*)d_in[3];
    const float* b1     = (const float*)d_in[4];
    const float* W2     = (const float*)d_in[5];
    const float* b2     = (const float*)d_in[6];
    const float* Ws     = (const float*)d_in[7];
    const float* bs     = (const float*)d_in[8];
    float* out = (float*)d_out;

    // workspace layout
    unsigned short* W1pT = (unsigned short*)d_ws;                       // 131072 B
    float* e1 = (float*)((char*)d_ws + 131072);                         // 65536 B
    float* vv = (float*)((char*)d_ws + 131072 + 65536);                 // 65536 B

    // kernel 0: fold term_weight into W1, transpose, bf16
    k_prep<<<(HH * DD) / 256, 256, 0, stream>>>(W1, tw, W1pT);

    // kernel 1: per-position e1 / v
    k_main<<<(BB * SS) / BM, 256, 0, stream>>>(hidden, W1pT, b1, W2, b2, Ws, e1, vv);

    // kernel 2: span scores
    k_span<<<(BB * SS) / 256, 256, 0, stream>>>(e1, vv, seqlen, bs, out);
}

// Round 3
// 118.040 us; speedup vs baseline: 1.1398x; 1.0570x over previous
//
#include <hip/hip_runtime.h>
#include <hip/hip_bf16.h>

// Problem constants
#define BB 32
#define SS 512
#define LL 8
#define HH 1024
#define DD 64

#define BM 16        // rows per block in main GEMM
#define ROWSTR 1032  // LDS row stride in bf16 elems (2064 B: 16B-aligned, bank stride 4 -> 2-way alias = free)

typedef __attribute__((ext_vector_type(8))) short bf16x8;
typedef __attribute__((ext_vector_type(8))) unsigned short u16x8;
typedef __attribute__((ext_vector_type(4))) float f32x4;

__device__ __forceinline__ unsigned short f2bf(float x) {
    unsigned int u = __float_as_uint(x);
    u += 0x7FFFu + ((u >> 16) & 1u);   // round-to-nearest-even
    return (unsigned short)(u >> 16);
}

// ---------------------------------------------------------------------------
// Kernel 0: fragment-major B pack.
// Bpack[(wv*32 + c)*64 + ln] (16 B per entry) = the b-fragment lane `ln` of
// wave `wv` needs at K-chunk `c` in k_main's MFMA loop:
//   n = wv*16 + (ln&15), k = (ln>>4)*8 + c*32 + j  (j = 0..7)
//   value = bf16(term_weight[k] * W1[k][n])
// Phase-2 loads become 1 KB fully-coalesced per instruction.
// ---------------------------------------------------------------------------
__global__ __launch_bounds__(256) void k_prep(const float* __restrict__ W1,
                                              const float* __restrict__ tw,
                                              unsigned short* __restrict__ Bpack) {
    int g = blockIdx.x * 256 + threadIdx.x;   // g < 4*32*64 = 8192
    int ln = g & 63;
    int c  = (g >> 6) & 31;
    int wv = g >> 11;
    int n  = wv * 16 + (ln & 15);
    int hb = (ln >> 4) * 8 + c * 32;
    u16x8 pk;
#pragma unroll
    for (int j = 0; j < 8; j++) {
        float val = tw[hb + j] * W1[(hb + j) * DD + n];
        pk[j] = f2bf(val);
    }
    *(u16x8*)(Bpack + (size_t)g * 8) = pk;
}

// ---------------------------------------------------------------------------
// Kernel 1: per-position e1 and v. Load-all-then-compute:
//   phase 1: stage full A-tile (16 rows x 1024 k, fp32->bf16) into LDS with
//            16 back-to-back float4 loads/thread; fuse v = hidden @ Ws.
//   barrier (the only one before epilogue)
//   phase 2: 32 barrier-free MFMA iterations; B fragments read coalesced from
//            packed global Bpack (L2-resident, 128 KB shared by all blocks).
// ---------------------------------------------------------------------------
__global__ __launch_bounds__(256, 4) void k_main(
        const float* __restrict__ hidden,
        const unsigned short* __restrict__ Bpack,
        const float* __restrict__ b1,
        const float* __restrict__ W2,
        const float* __restrict__ b2,
        const float* __restrict__ Ws,
        float* __restrict__ e1,
        float* __restrict__ vout) {
    __shared__ unsigned short Alds[BM * ROWSTR];   // 33024 B
    __shared__ float eplds[4][BM];                 // 256 B

    const int tid = threadIdx.x;
    const int row0 = blockIdx.x * BM;

    // ---- phase 1: stage A + fused v partial ----
    {
        const int r  = tid >> 4;          // 0..15: which row this thread stages
        const int co = (tid & 15) * 4;    // float offset within 64-float segment
        const float* arow = hidden + (size_t)(row0 + r) * HH + co;
        float vp = 0.f;
#pragma unroll
        for (int i = 0; i < 16; i++) {
            float4 h4 = *(const float4*)(arow + i * 64);
            float4 w4 = *(const float4*)(Ws + co + i * 64);
            vp += h4.x * w4.x + h4.y * w4.y + h4.z * w4.z + h4.w * w4.w;
            ushort4 a4;
            a4.x = f2bf(h4.x); a4.y = f2bf(h4.y); a4.z = f2bf(h4.z); a4.w = f2bf(h4.w);
            *(ushort4*)&Alds[r * ROWSTR + co + i * 64] = a4;
        }
        // v reduction across the 16 threads sharing a row
        vp += __shfl_xor(vp, 1);
        vp += __shfl_xor(vp, 2);
        vp += __shfl_xor(vp, 4);
        vp += __shfl_xor(vp, 8);
        if ((tid & 15) == 0) vout[row0 + r] = vp;
    }
    __syncthreads();

    // ---- phase 2: barrier-free MFMA loop, coalesced packed-B loads ----
    const int wv   = tid >> 6;     // wave 0..3 -> cols 16w..16w+15
    const int ln   = tid & 63;
    const int ln15 = ln & 15;
    const int quad = ln >> 4;

    const unsigned short* bptr = Bpack + ((size_t)(wv * 32) * 64 + ln) * 8;
    const unsigned short* aptr = &Alds[ln15 * ROWSTR + quad * 8];

    f32x4 acc = {0.f, 0.f, 0.f, 0.f};
#pragma unroll
    for (int c = 0; c < 32; c++) {
        bf16x8 bfrag = *(const bf16x8*)(bptr + c * 512);   // 64 lanes x 16 B contiguous
        bf16x8 afrag = *(const bf16x8*)(aptr + c * 32);
        acc = __builtin_amdgcn_mfma_f32_16x16x32_bf16(afrag, bfrag, acc, 0, 0, 0);
    }

    // ---- epilogue: relu(x + b1) * W2, reduce over this wave's 16 cols ----
    const int col = wv * 16 + ln15;
    const float b1c = b1[col];
    const float w2c = W2[col];
    float ep[4];
#pragma unroll
    for (int reg = 0; reg < 4; reg++) {
        ep[reg] = fmaxf(acc[reg] + b1c, 0.f) * w2c;
    }
#pragma unroll
    for (int off = 1; off < 16; off <<= 1) {
#pragma unroll
        for (int i = 0; i < 4; i++) ep[i] += __shfl_xor(ep[i], off);
    }
    if (ln15 == 0) {
#pragma unroll
        for (int reg = 0; reg < 4; reg++) eplds[wv][quad * 4 + reg] = ep[reg];
    }
    __syncthreads();
    if (tid < BM) {
        e1[row0 + tid] = b2[0] + eplds[0][tid] + eplds[1][tid] + eplds[2][tid] + eplds[3][tid];
    }
}

// ---------------------------------------------------------------------------
// Kernel 2: span scoring. One thread per (b, s). Online softmax over j<=l.
// ---------------------------------------------------------------------------
__global__ __launch_bounds__(256) void k_span(
        const float* __restrict__ e1,
        const float* __restrict__ v,
        const int* __restrict__ seq_lengths,
        const float* __restrict__ bs,
        float* __restrict__ out) {
    int i = blockIdx.x * 256 + threadIdx.x;   // i < B*S
    int b = i >> 9;
    int s = i & (SS - 1);
    int sl = seq_lengths[b];
    float res[LL];

    if (s >= sl) {
#pragma unroll
        for (int l = 0; l < LL; l++) res[l] = 0.f;
    } else {
        const float bsv = bs[0];
        float e[LL], vv[LL];
        int base = b << 9;
#pragma unroll
        for (int j = 0; j < LL; j++) {
            int pos = s + j; if (pos > SS - 1) pos = SS - 1;
            e[j]  = e1[base + pos];
            vv[j] = v[base + pos];
        }
        // j = 0 is always valid when s < sl
        float M = e[0], Z = 1.f, W = vv[0];
        res[0] = W / Z + bsv;
#pragma unroll
        for (int l = 1; l < LL; l++) {
            if (s + l < sl) {
                float el = e[l];
                if (el > M) {
                    float c = __expf(M - el);
                    Z = Z * c + 1.f;
                    W = W * c + vv[l];
                    M = el;
                } else {
                    float p = __expf(el - M);
                    Z += p;
                    W += p * vv[l];
                }
            }
            res[l] = W / Z + bsv;
        }
    }
    float4* o = (float4*)(out + (size_t)i * LL);
    o[0] = make_float4(res[0], res[1], res[2], res[3]);
    o[1] = make_float4(res[4], res[5], res[6], res[7]);
}

extern "C" void kernel_launch(void* const* d_in, const int* in_sizes, int n_in,
                              void* d_out, int out_size, void* d_ws, size_t ws_size,
                              hipStream_t stream) {
    const float* hidden = (const float*)d_in[0];
    const int*   seqlen = (const int*)d_in[1];
    const float* tw     = (const float*)d_in[2];
    const float* W1     = (const float*)d_in[3];
    const float* b1     = (const float*)d_in[4];
    const float* W2     = (const float*)d_in[5];
    const float* b2     = (const float*)d_in[6];
    const float* Ws     = (const float*)d_in[7];
    const float* bs     = (const float*)d_in[8];
    float* out = (float*)d_out;

    // workspace layout
    unsigned short* Bpack = (unsigned short*)d_ws;                      // 131072 B
    float* e1 = (float*)((char*)d_ws + 131072);                         // 65536 B
    float* vv = (float*)((char*)d_ws + 131072 + 65536);                 // 65536 B

    // kernel 0: fold term_weight into W1, pack fragment-major, bf16
    k_prep<<<32, 256, 0, stream>>>(W1, tw, Bpack);

    // kernel 1: per-position e1 / v
    k_main<<<(BB * SS) / BM, 256, 0, stream>>>(hidden, Bpack, b1, W2, b2, Ws, e1, vv);

    // kernel 2: span scores
    k_span<<<(BB * SS) / 256, 256, 0, stream>>>(e1, vv, seqlen, bs, out);
}

// Round 4
// 114.733 us; speedup vs baseline: 1.1726x; 1.0288x over previous
//
#include <hip/hip_runtime.h>
#include <hip/hip_bf16.h>

// Problem constants
#define BB 32
#define SS 512
#define LL 8
#define HH 1024
#define DD 64

#define BM 16        // rows per block in main GEMM
#define ROWSTR 1032  // LDS row stride in bf16 elems (2064 B: 16B-aligned; phase-2 read
                     // pattern is uniform 8 lanes per 4-bank group = b128 minimum, conflict-free)

typedef __attribute__((ext_vector_type(8))) short bf16x8;
typedef __attribute__((ext_vector_type(8))) unsigned short u16x8;
typedef __attribute__((ext_vector_type(4))) float f32x4;

__device__ __forceinline__ unsigned short f2bf(float x) {
    unsigned int u = __float_as_uint(x);
    u += 0x7FFFu + ((u >> 16) & 1u);   // round-to-nearest-even
    return (unsigned short)(u >> 16);
}

// ---------------------------------------------------------------------------
// Kernel 0: fragment-major B pack.
// Bpack[(wv*32 + c)*64 + ln] (16 B per entry) = the b-fragment lane `ln` of
// wave `wv` needs at K-chunk `c` in k_main's MFMA loop:
//   n = wv*16 + (ln&15), k = (ln>>4)*8 + c*32 + j  (j = 0..7)
//   value = bf16(term_weight[k] * W1[k][n])
// ---------------------------------------------------------------------------
__global__ __launch_bounds__(256) void k_prep(const float* __restrict__ W1,
                                              const float* __restrict__ tw,
                                              unsigned short* __restrict__ Bpack) {
    int g = blockIdx.x * 256 + threadIdx.x;   // g < 4*32*64 = 8192
    int ln = g & 63;
    int c  = (g >> 6) & 31;
    int wv = g >> 11;
    int n  = wv * 16 + (ln & 15);
    int hb = (ln >> 4) * 8 + c * 32;
    u16x8 pk;
#pragma unroll
    for (int j = 0; j < 8; j++) {
        float val = tw[hb + j] * W1[(hb + j) * DD + n];
        pk[j] = f2bf(val);
    }
    *(u16x8*)(Bpack + (size_t)g * 8) = pk;
}

// ---------------------------------------------------------------------------
// Kernel 1: per-position e1 and v.
//   phase 1: hoist ALL 16 float4 A-loads into registers (forces 16 outstanding
//            HBM/L3 loads per thread), then convert->LDS + fused v = h @ Ws.
//   phase 2: barrier-free MFMA loop; B fragments from packed global Bpack
//            (L2-resident) with explicit 4-deep rolling prefetch.
// LDS 33 KB -> 4 blocks/CU; launch_bounds(256,4) -> 128 VGPR cap, hoist fits.
// ---------------------------------------------------------------------------
__global__ __launch_bounds__(256, 4) void k_main(
        const float* __restrict__ hidden,
        const unsigned short* __restrict__ Bpack,
        const float* __restrict__ b1,
        const float* __restrict__ W2,
        const float* __restrict__ b2,
        const float* __restrict__ Ws,
        float* __restrict__ e1,
        float* __restrict__ vout) {
    __shared__ unsigned short Alds[BM * ROWSTR];   // 33024 B
    __shared__ float eplds[4][BM];                 // 256 B

    const int tid = threadIdx.x;
    const int row0 = blockIdx.x * BM;

    // ---- phase 1: deep-pipelined A stage + fused v partial ----
    {
        const int r  = tid >> 4;          // 0..15: which row this thread stages
        const int co = (tid & 15) * 4;    // float offset within 64-float segment
        const float* arow = hidden + (size_t)(row0 + r) * HH + co;
        float4 h[16];
#pragma unroll
        for (int i = 0; i < 16; i++) h[i] = *(const float4*)(arow + i * 64);

        float vp = 0.f;
#pragma unroll
        for (int i = 0; i < 16; i++) {
            float4 w4 = *(const float4*)(Ws + co + i * 64);
            vp += h[i].x * w4.x + h[i].y * w4.y + h[i].z * w4.z + h[i].w * w4.w;
            ushort4 a4;
            a4.x = f2bf(h[i].x); a4.y = f2bf(h[i].y);
            a4.z = f2bf(h[i].z); a4.w = f2bf(h[i].w);
            *(ushort4*)&Alds[r * ROWSTR + co + i * 64] = a4;
        }
        // v reduction across the 16 threads sharing a row
        vp += __shfl_xor(vp, 1);
        vp += __shfl_xor(vp, 2);
        vp += __shfl_xor(vp, 4);
        vp += __shfl_xor(vp, 8);
        if ((tid & 15) == 0) vout[row0 + r] = vp;
    }
    __syncthreads();

    // ---- phase 2: barrier-free MFMA loop, 4-deep B prefetch ----
    const int wv   = tid >> 6;     // wave 0..3 -> cols 16w..16w+15
    const int ln   = tid & 63;
    const int ln15 = ln & 15;
    const int quad = ln >> 4;

    const unsigned short* bptr = Bpack + ((size_t)(wv * 32) * 64 + ln) * 8;
    const unsigned short* aptr = &Alds[ln15 * ROWSTR + quad * 8];

    bf16x8 bf[4];
#pragma unroll
    for (int i = 0; i < 4; i++) bf[i] = *(const bf16x8*)(bptr + i * 512);

    f32x4 acc = {0.f, 0.f, 0.f, 0.f};
#pragma unroll
    for (int c = 0; c < 32; c++) {
        bf16x8 bcur = bf[c & 3];
        if (c + 4 < 32) bf[c & 3] = *(const bf16x8*)(bptr + (c + 4) * 512);
        bf16x8 afrag = *(const bf16x8*)(aptr + c * 32);
        acc = __builtin_amdgcn_mfma_f32_16x16x32_bf16(afrag, bcur, acc, 0, 0, 0);
    }

    // ---- epilogue: relu(x + b1) * W2, reduce over this wave's 16 cols ----
    const int col = wv * 16 + ln15;
    const float b1c = b1[col];
    const float w2c = W2[col];
    float ep[4];
#pragma unroll
    for (int reg = 0; reg < 4; reg++) {
        ep[reg] = fmaxf(acc[reg] + b1c, 0.f) * w2c;
    }
#pragma unroll
    for (int off = 1; off < 16; off <<= 1) {
#pragma unroll
        for (int i = 0; i < 4; i++) ep[i] += __shfl_xor(ep[i], off);
    }
    if (ln15 == 0) {
#pragma unroll
        for (int reg = 0; reg < 4; reg++) eplds[wv][quad * 4 + reg] = ep[reg];
    }
    __syncthreads();
    if (tid < BM) {
        e1[row0 + tid] = b2[0] + eplds[0][tid] + eplds[1][tid] + eplds[2][tid] + eplds[3][tid];
    }
}

// ---------------------------------------------------------------------------
// Kernel 2: span scoring. One thread per (b, s). Online softmax over j<=l.
// ---------------------------------------------------------------------------
__global__ __launch_bounds__(256) void k_span(
        const float* __restrict__ e1,
        const float* __restrict__ v,
        const int* __restrict__ seq_lengths,
        const float* __restrict__ bs,
        float* __restrict__ out) {
    int i = blockIdx.x * 256 + threadIdx.x;   // i < B*S
    int b = i >> 9;
    int s = i & (SS - 1);
    int sl = seq_lengths[b];
    float res[LL];

    if (s >= sl) {
#pragma unroll
        for (int l = 0; l < LL; l++) res[l] = 0.f;
    } else {
        const float bsv = bs[0];
        float e[LL], vv[LL];
        int base = b << 9;
#pragma unroll
        for (int j = 0; j < LL; j++) {
            int pos = s + j; if (pos > SS - 1) pos = SS - 1;
            e[j]  = e1[base + pos];
            vv[j] = v[base + pos];
        }
        // j = 0 is always valid when s < sl
        float M = e[0], Z = 1.f, W = vv[0];
        res[0] = W / Z + bsv;
#pragma unroll
        for (int l = 1; l < LL; l++) {
            if (s + l < sl) {
                float el = e[l];
                if (el > M) {
                    float c = __expf(M - el);
                    Z = Z * c + 1.f;
                    W = W * c + vv[l];
                    M = el;
                } else {
                    float p = __expf(el - M);
                    Z += p;
                    W += p * vv[l];
                }
            }
            res[l] = W / Z + bsv;
        }
    }
    float4* o = (float4*)(out + (size_t)i * LL);
    o[0] = make_float4(res[0], res[1], res[2], res[3]);
    o[1] = make_float4(res[4], res[5], res[6], res[7]);
}

extern "C" void kernel_launch(void* const* d_in, const int* in_sizes, int n_in,
                              void* d_out, int out_size, void* d_ws, size_t ws_size,
                              hipStream_t stream) {
    const float* hidden = (const float*)d_in[0];
    const int*   seqlen = (const int*)d_in[1];
    const float* tw     = (const float*)d_in[2];
    const float* W1     = (const float*)d_in[3];
    const float* b1     = (const float*)d_in[4];
    const float* W2     = (const float*)d_in[5];
    const float* b2     = (const float*)d_in[6];
    const float* Ws     = (const float*)d_in[7];
    const float* bs     = (const float*)d_in[8];
    float* out = (float*)d_out;

    // workspace layout
    unsigned short* Bpack = (unsigned short*)d_ws;                      // 131072 B
    float* e1 = (float*)((char*)d_ws + 131072);                         // 65536 B
    float* vv = (float*)((char*)d_ws + 131072 + 65536);                 // 65536 B

    // kernel 0: fold term_weight into W1, pack fragment-major, bf16
    k_prep<<<32, 256, 0, stream>>>(W1, tw, Bpack);

    // kernel 1: per-position e1 / v
    k_main<<<(BB * SS) / BM, 256, 0, stream>>>(hidden, Bpack, b1, W2, b2, Ws, e1, vv);

    // kernel 2: span scores
    k_span<<<(BB * SS) / 256, 256, 0, stream>>>(e1, vv, seqlen, bs, out);
}

// Round 5
// 114.455 us; speedup vs baseline: 1.1755x; 1.0024x over previous
//
#include <hip/hip_runtime.h>
#include <hip/hip_bf16.h>

// Problem constants
#define BB 32
#define SS 512
#define LL 8
#define HH 1024
#define DD 64

#define BM 64        // rows per block in main GEMM (1 block/CU, 256 blocks total)
#define ROWSTR 1032  // LDS row stride in bf16 elems (2064 B: 16B-aligned; phase-2 read
                     // pattern is uniform 8 lanes per 4-bank group = b128 minimum, conflict-free)

typedef __attribute__((ext_vector_type(8))) short bf16x8;
typedef __attribute__((ext_vector_type(8))) unsigned short u16x8;
typedef __attribute__((ext_vector_type(4))) float f32x4;

__device__ __forceinline__ unsigned short f2bf(float x) {
    unsigned int u = __float_as_uint(x);
    u += 0x7FFFu + ((u >> 16) & 1u);   // round-to-nearest-even
    return (unsigned short)(u >> 16);
}

// ---------------------------------------------------------------------------
// Kernel 0: fragment-major B pack.
// Bpack[(cg*32 + c)*64 + ln] (16 B per entry) = the b-fragment lane `ln` of
// col-group `cg` needs at K-chunk `c` in k_main's MFMA loop:
//   n = cg*16 + (ln&15), k = (ln>>4)*8 + c*32 + j  (j = 0..7)
//   value = bf16(term_weight[k] * W1[k][n])
// ---------------------------------------------------------------------------
__global__ __launch_bounds__(256) void k_prep(const float* __restrict__ W1,
                                              const float* __restrict__ tw,
                                              unsigned short* __restrict__ Bpack) {
    int g = blockIdx.x * 256 + threadIdx.x;   // g < 4*32*64 = 8192
    int ln = g & 63;
    int c  = (g >> 6) & 31;
    int cg = g >> 11;
    int n  = cg * 16 + (ln & 15);
    int hb = (ln >> 4) * 8 + c * 32;
    u16x8 pk;
#pragma unroll
    for (int j = 0; j < 8; j++) {
        float val = tw[hb + j] * W1[(hb + j) * DD + n];
        pk[j] = f2bf(val);
    }
    *(u16x8*)(Bpack + (size_t)g * 8) = pk;
}

// ---------------------------------------------------------------------------
// Kernel 1: per-position e1 and v. BM=64 rows/block, 1024 thr (16 waves as
// 4 row-groups x 4 col-groups of 16x16 MFMA tiles).
//   phase 1: hoist ALL 16 float4 A-loads into registers (16 outstanding
//            loads/thread), then convert->LDS + fused v = h @ Ws.
//   phase 2: barrier-free MFMA loop; B fragments from packed global Bpack
//            (L2-resident; 128 KB/block x 256 blocks = 33.5 MB L2 traffic)
//            with explicit 4-deep rolling prefetch.
// LDS 129 KB + 1 KB -> 1 block/CU; 16 waves/CU (same occupancy as BM=16 x4).
// ---------------------------------------------------------------------------
__global__ __launch_bounds__(1024, 1) void k_main(
        const float* __restrict__ hidden,
        const unsigned short* __restrict__ Bpack,
        const float* __restrict__ b1,
        const float* __restrict__ W2,
        const float* __restrict__ b2,
        const float* __restrict__ Ws,
        float* __restrict__ e1,
        float* __restrict__ vout) {
    __shared__ unsigned short Alds[BM * ROWSTR];   // 132096 B
    __shared__ float eplds[4][BM];                 // 1024 B

    const int tid = threadIdx.x;
    const int row0 = blockIdx.x * BM;

    // ---- phase 1: deep-pipelined A stage + fused v partial ----
    {
        const int r  = tid >> 4;          // 0..63: which row this thread stages
        const int co = (tid & 15) * 4;    // float offset within 64-float segment
        const float* arow = hidden + (size_t)(row0 + r) * HH + co;
        float4 h[16];
#pragma unroll
        for (int i = 0; i < 16; i++) h[i] = *(const float4*)(arow + i * 64);

        float vp = 0.f;
#pragma unroll
        for (int i = 0; i < 16; i++) {
            float4 w4 = *(const float4*)(Ws + co + i * 64);
            vp += h[i].x * w4.x + h[i].y * w4.y + h[i].z * w4.z + h[i].w * w4.w;
            ushort4 a4;
            a4.x = f2bf(h[i].x); a4.y = f2bf(h[i].y);
            a4.z = f2bf(h[i].z); a4.w = f2bf(h[i].w);
            *(ushort4*)&Alds[r * ROWSTR + co + i * 64] = a4;
        }
        // v reduction across the 16 threads sharing a row
        vp += __shfl_xor(vp, 1);
        vp += __shfl_xor(vp, 2);
        vp += __shfl_xor(vp, 4);
        vp += __shfl_xor(vp, 8);
        if ((tid & 15) == 0) vout[row0 + r] = vp;
    }
    __syncthreads();

    // ---- phase 2: barrier-free MFMA loop, 4-deep B prefetch ----
    const int wv   = tid >> 6;     // wave 0..15
    const int rg   = wv >> 2;      // row-group: rows 16*rg .. 16*rg+15
    const int cg   = wv & 3;       // col-group: cols 16*cg .. 16*cg+15
    const int ln   = tid & 63;
    const int ln15 = ln & 15;
    const int quad = ln >> 4;

    const unsigned short* bptr = Bpack + ((size_t)(cg * 32) * 64 + ln) * 8;
    const unsigned short* aptr = &Alds[(rg * 16 + ln15) * ROWSTR + quad * 8];

    bf16x8 bf[4];
#pragma unroll
    for (int i = 0; i < 4; i++) bf[i] = *(const bf16x8*)(bptr + i * 512);

    f32x4 acc = {0.f, 0.f, 0.f, 0.f};
#pragma unroll
    for (int c = 0; c < 32; c++) {
        bf16x8 bcur = bf[c & 3];
        if (c + 4 < 32) bf[c & 3] = *(const bf16x8*)(bptr + (c + 4) * 512);
        bf16x8 afrag = *(const bf16x8*)(aptr + c * 32);
        acc = __builtin_amdgcn_mfma_f32_16x16x32_bf16(afrag, bcur, acc, 0, 0, 0);
    }

    // ---- epilogue: relu(x + b1) * W2, reduce over this wave's 16 cols ----
    const int col = cg * 16 + ln15;
    const float b1c = b1[col];
    const float w2c = W2[col];
    float ep[4];
#pragma unroll
    for (int reg = 0; reg < 4; reg++) {
        ep[reg] = fmaxf(acc[reg] + b1c, 0.f) * w2c;
    }
#pragma unroll
    for (int off = 1; off < 16; off <<= 1) {
#pragma unroll
        for (int i = 0; i < 4; i++) ep[i] += __shfl_xor(ep[i], off);
    }
    if (ln15 == 0) {
#pragma unroll
        for (int reg = 0; reg < 4; reg++)
            eplds[cg][rg * 16 + quad * 4 + reg] = ep[reg];
    }
    __syncthreads();
    if (tid < BM) {
        e1[row0 + tid] = b2[0] + eplds[0][tid] + eplds[1][tid] + eplds[2][tid] + eplds[3][tid];
    }
}

// ---------------------------------------------------------------------------
// Kernel 2: span scoring. One thread per (b, s). Online softmax over j<=l.
// ---------------------------------------------------------------------------
__global__ __launch_bounds__(256) void k_span(
        const float* __restrict__ e1,
        const float* __restrict__ v,
        const int* __restrict__ seq_lengths,
        const float* __restrict__ bs,
        float* __restrict__ out) {
    int i = blockIdx.x * 256 + threadIdx.x;   // i < B*S
    int b = i >> 9;
    int s = i & (SS - 1);
    int sl = seq_lengths[b];
    float res[LL];

    if (s >= sl) {
#pragma unroll
        for (int l = 0; l < LL; l++) res[l] = 0.f;
    } else {
        const float bsv = bs[0];
        float e[LL], vv[LL];
        int base = b << 9;
#pragma unroll
        for (int j = 0; j < LL; j++) {
            int pos = s + j; if (pos > SS - 1) pos = SS - 1;
            e[j]  = e1[base + pos];
            vv[j] = v[base + pos];
        }
        // j = 0 is always valid when s < sl
        float M = e[0], Z = 1.f, W = vv[0];
        res[0] = W / Z + bsv;
#pragma unroll
        for (int l = 1; l < LL; l++) {
            if (s + l < sl) {
                float el = e[l];
                if (el > M) {
                    float c = __expf(M - el);
                    Z = Z * c + 1.f;
                    W = W * c + vv[l];
                    M = el;
                } else {
                    float p = __expf(el - M);
                    Z += p;
                    W += p * vv[l];
                }
            }
            res[l] = W / Z + bsv;
        }
    }
    float4* o = (float4*)(out + (size_t)i * LL);
    o[0] = make_float4(res[0], res[1], res[2], res[3]);
    o[1] = make_float4(res[4], res[5], res[6], res[7]);
}

extern "C" void kernel_launch(void* const* d_in, const int* in_sizes, int n_in,
                              void* d_out, int out_size, void* d_ws, size_t ws_size,
                              hipStream_t stream) {
    const float* hidden = (const float*)d_in[0];
    const int*   seqlen = (const int*)d_in[1];
    const float* tw     = (const float*)d_in[2];
    const float* W1     = (const float*)d_in[3];
    const float* b1     = (const float*)d_in[4];
    const float* W2     = (const float*)d_in[5];
    const float* b2     = (const float*)d_in[6];
    const float* Ws     = (const float*)d_in[7];
    const float* bs     = (const float*)d_in[8];
    float* out = (float*)d_out;

    // workspace layout
    unsigned short* Bpack = (unsigned short*)d_ws;                      // 131072 B
    float* e1 = (float*)((char*)d_ws + 131072);                         // 65536 B
    float* vv = (float*)((char*)d_ws + 131072 + 65536);                 // 65536 B

    // kernel 0: fold term_weight into W1, pack fragment-major, bf16
    k_prep<<<32, 256, 0, stream>>>(W1, tw, Bpack);

    // kernel 1: per-position e1 / v
    k_main<<<(BB * SS) / BM, 1024, 0, stream>>>(hidden, Bpack, b1, W2, b2, Ws, e1, vv);

    // kernel 2: span scores
    k_span<<<(BB * SS) / 256, 256, 0, stream>>>(e1, vv, seqlen, bs, out);
}